// Round 1
// baseline (57581.311 us; speedup 1.0000x reference)
//
#include <hip/hip_runtime.h>
#include <hip/hip_bf16.h>

// Problem constants
#define B_SZ 512
#define T_SZ 512
#define D_SZ 256
#define H_SZ 200
#define G4   800   // 4*H

// ---------------------------------------------------------------------------
// Kernel 1: pre[b][tc][g] = sum_d x[b][t0+tc][d] * W_ih[g][d] + b_ih[g] + b_hh[g]
// GEMM: M = 512*C_T (m = b*C_T + tc), N = 800 (padded to 832 = 13 tiles of 64), K = 256
// Block 256 threads, tile 128(M) x 64(N), K-chunk 16. fp32 VALU.
// ---------------------------------------------------------------------------
__global__ __launch_bounds__(256)
void pre_gemm(const float* __restrict__ x, const float* __restrict__ Wih,
              const float* __restrict__ bih, const float* __restrict__ bhh,
              float* __restrict__ pre, int t0, int ct_log2)
{
    const int C_T = 1 << ct_log2;
    const int nt = blockIdx.x % 13;
    const int mt = blockIdx.x / 13;
    const int m0 = mt * 128, n0 = nt * 64;

    __shared__ float As[128 * 16];   // swizzled [r][(k + 4*((r>>3)&3)) & 15]
    __shared__ float Bs[16 * 68];    // [k][n], stride 68 (16B-aligned float4 reads)

    const int tid = threadIdx.x;
    const int tm = tid >> 4;         // 0..15 -> 8 M-rows each
    const int tn = tid & 15;         // 0..15 -> 4 N-cols each

    float acc[8][4];
    #pragma unroll
    for (int i = 0; i < 8; ++i)
        #pragma unroll
        for (int j = 0; j < 4; ++j) acc[i][j] = 0.f;

    // A-load mapping: thread -> row r (0..127), k-half kh (0 or 8)
    const int r  = tid >> 1;
    const int kh = (tid & 1) * 8;
    const int m  = m0 + r;
    const int bb = m >> ct_log2;
    const int tc = m & (C_T - 1);
    const float* xrow_base = x + ((size_t)(bb * T_SZ + t0 + tc) << 8);
    const int rotA = 4 * ((r >> 3) & 3);

    // B-load mapping: thread -> n-row nb (0..63), k-quarter kb
    const int nb = tid >> 2;
    const int kb = (tid & 3) * 4;
    const bool bvalid = (n0 + nb) < G4;
    const float* wrow_base = Wih + (size_t)(n0 + nb) * D_SZ;

    for (int k0 = 0; k0 < D_SZ; k0 += 16) {
        // global loads into regs
        float4 av0 = *(const float4*)(xrow_base + k0 + kh);
        float4 av1 = *(const float4*)(xrow_base + k0 + kh + 4);
        float4 bv;
        if (bvalid) bv = *(const float4*)(wrow_base + k0 + kb);
        else        bv = make_float4(0.f, 0.f, 0.f, 0.f);

        __syncthreads();   // previous compute done before LDS overwrite

        // store A (swizzled, float4, aligned since rotA % 4 == 0)
        *(float4*)&As[r * 16 + ((kh     + rotA) & 15)] = av0;
        *(float4*)&As[r * 16 + ((kh + 4 + rotA) & 15)] = av1;
        // store B transposed: Bs[k][n]
        Bs[(kb + 0) * 68 + nb] = bv.x;
        Bs[(kb + 1) * 68 + nb] = bv.y;
        Bs[(kb + 2) * 68 + nb] = bv.z;
        Bs[(kb + 3) * 68 + nb] = bv.w;

        __syncthreads();

        const int rotR = 4 * (tm & 3);
        #pragma unroll
        for (int kg = 0; kg < 4; ++kg) {
            float4 bf[4];
            #pragma unroll
            for (int j = 0; j < 4; ++j)
                bf[j] = *(const float4*)&Bs[(kg * 4 + j) * 68 + tn * 4];
            #pragma unroll
            for (int i = 0; i < 8; ++i) {
                const float4 af = *(const float4*)&As[(tm * 8 + i) * 16 + ((kg * 4 + rotR) & 15)];
                acc[i][0] += af.x * bf[0].x + af.y * bf[1].x + af.z * bf[2].x + af.w * bf[3].x;
                acc[i][1] += af.x * bf[0].y + af.y * bf[1].y + af.z * bf[2].y + af.w * bf[3].y;
                acc[i][2] += af.x * bf[0].z + af.y * bf[1].z + af.z * bf[2].z + af.w * bf[3].z;
                acc[i][3] += af.x * bf[0].w + af.y * bf[1].w + af.z * bf[2].w + af.w * bf[3].w;
            }
        }
    }

    // epilogue: add biases, store
    const int n = n0 + tn * 4;
    if (n < G4) {
        const float4 bi = *(const float4*)(bih + n);
        const float4 bh = *(const float4*)(bhh + n);
        const float4 badd = make_float4(bi.x + bh.x, bi.y + bh.y, bi.z + bh.z, bi.w + bh.w);
        #pragma unroll
        for (int i = 0; i < 8; ++i) {
            const size_t mm = (size_t)(m0 + tm * 8 + i);
            float4 v = make_float4(acc[i][0] + badd.x, acc[i][1] + badd.y,
                                   acc[i][2] + badd.z, acc[i][3] + badd.w);
            *(float4*)(pre + mm * G4 + n) = v;
        }
    }
}

// ---------------------------------------------------------------------------
// Kernel 2: LSTM recurrence, one workgroup per batch element (512 WGs, 2/CU).
// 448 threads; threads 0..399 own W_hh rows t_ and t_+400 in registers (400 VGPRs).
// h in LDS (float4 broadcast reads feed 8 FMAs each); c + out-acc in registers.
// ---------------------------------------------------------------------------
__device__ __forceinline__ float sigm(float v) { return 1.f / (1.f + __expf(-v)); }

__global__ __launch_bounds__(448, 1)
void lstm_rec(const float* __restrict__ pre,   // [512][C_T][800]
              const float* __restrict__ Whh,   // [800][200]
              const float* __restrict__ Wout,  // [102400]
              const float* __restrict__ bout,  // [1]
              float* __restrict__ state,       // h[512][256], c[512][256], oa[512][256]
              float* __restrict__ out,         // [512]
              int t0, int C_T)
{
    const int b  = blockIdx.x;
    const int t_ = threadIdx.x;

    __shared__ float h_sh[256];
    __shared__ float gates[800];

    // register-resident weights: rows t_ and t_+400
    float w[400];
    if (t_ < 400) {
        const float4* w0 = (const float4*)(Whh + (size_t)t_ * H_SZ);
        const float4* w1 = (const float4*)(Whh + (size_t)(t_ + 400) * H_SZ);
        #pragma unroll
        for (int i = 0; i < 50; ++i) {
            float4 v = w0[i];
            w[4 * i + 0] = v.x; w[4 * i + 1] = v.y; w[4 * i + 2] = v.z; w[4 * i + 3] = v.w;
        }
        #pragma unroll
        for (int i = 0; i < 50; ++i) {
            float4 v = w1[i];
            w[200 + 4 * i + 0] = v.x; w[200 + 4 * i + 1] = v.y;
            w[200 + 4 * i + 2] = v.z; w[200 + 4 * i + 3] = v.w;
        }
    }

    float* h_st  = state + (size_t)b * 256;
    float* c_st  = state + (size_t)B_SZ * 256 + (size_t)b * 256;
    float* oa_st = state + (size_t)2 * B_SZ * 256 + (size_t)b * 256;

    float c_reg = 0.f, oa = 0.f;
    if (t0 == 0) {
        if (t_ < 256) h_sh[t_] = 0.f;
    } else {
        if (t_ < 256) h_sh[t_] = h_st[t_];
        if (t_ < H_SZ) { c_reg = c_st[t_]; oa = oa_st[t_]; }
    }
    __syncthreads();

    for (int tc = 0; tc < C_T; ++tc) {
        const int t = t0 + tc;
        if (t_ < 400) {
            const float4* h4 = (const float4*)h_sh;
            float a0 = 0.f, a1 = 0.f, a2 = 0.f, a3 = 0.f;
            float b0 = 0.f, b1 = 0.f, b2 = 0.f, b3 = 0.f;
            #pragma unroll
            for (int i = 0; i < 50; ++i) {
                const float4 hv = h4[i];
                a0 += w[4 * i + 0] * hv.x; a1 += w[4 * i + 1] * hv.y;
                a2 += w[4 * i + 2] * hv.z; a3 += w[4 * i + 3] * hv.w;
                b0 += w[200 + 4 * i + 0] * hv.x; b1 += w[200 + 4 * i + 1] * hv.y;
                b2 += w[200 + 4 * i + 2] * hv.z; b3 += w[200 + 4 * i + 3] * hv.w;
            }
            const float* prow = pre + ((size_t)b * C_T + tc) * G4;
            const float x0 = (a0 + a1) + (a2 + a3) + prow[t_];
            const float x1 = (b0 + b1) + (b2 + b3) + prow[t_ + 400];
            // rows 0..399: i (sigmoid) / f (sigmoid); rows 400..799: g (tanh) / o (sigmoid)
            const float act0 = sigm(x0);
            float act1;
            if (t_ < H_SZ) act1 = 2.f * sigm(2.f * x1) - 1.f;   // tanh(g)
            else           act1 = sigm(x1);                      // o
            gates[t_]       = act0;
            gates[t_ + 400] = act1;
        }
        __syncthreads();
        if (t_ < H_SZ) {
            const float ig = gates[t_], fg = gates[H_SZ + t_];
            const float gg = gates[2 * H_SZ + t_], og = gates[3 * H_SZ + t_];
            const float cn = fg * c_reg + ig * gg;
            c_reg = cn;
            const float hn = og * (2.f * sigm(2.f * cn) - 1.f);  // o * tanh(c)
            h_sh[t_] = hn;
            oa += hn * Wout[(size_t)t * H_SZ + t_];
        }
        __syncthreads();
    }

    if (t0 + C_T >= T_SZ) {
        // final reduction of output accumulator over 200 threads
        if (t_ < H_SZ) gates[t_] = oa;
        __syncthreads();
        if (t_ < 64) {
            float s = gates[t_] + gates[t_ + 64] + gates[t_ + 128];
            if (t_ < 8) s += gates[t_ + 192];
            #pragma unroll
            for (int off = 32; off; off >>= 1) s += __shfl_down(s, off);
            if (t_ == 0) out[b] = s + bout[0];
        }
    } else {
        if (t_ < 256) h_st[t_] = h_sh[t_];
        if (t_ < H_SZ) { c_st[t_] = c_reg; oa_st[t_] = oa; }
    }
}

// ---------------------------------------------------------------------------
extern "C" void kernel_launch(void* const* d_in, const int* in_sizes, int n_in,
                              void* d_out, int out_size, void* d_ws, size_t ws_size,
                              hipStream_t stream)
{
    const float* x    = (const float*)d_in[0];
    const float* Wih  = (const float*)d_in[1];
    const float* Whh  = (const float*)d_in[2];
    const float* bih  = (const float*)d_in[3];
    const float* bhh  = (const float*)d_in[4];
    const float* Wout = (const float*)d_in[5];
    const float* bout = (const float*)d_in[6];
    float* out = (float*)d_out;

    // ws layout: [state: 3 * 512 * 256 fp32][pre: 512 * C_T * 800 fp32]
    const size_t state_bytes = (size_t)3 * B_SZ * 256 * sizeof(float);
    float* state = (float*)d_ws;
    float* pre   = (float*)((char*)d_ws + state_bytes);

    // pick largest power-of-two time-chunk that fits the workspace
    int ct = 512;
    while (ct > 8 &&
           state_bytes + (size_t)B_SZ * ct * G4 * sizeof(float) > ws_size)
        ct >>= 1;
    int ct_log2 = 0;
    while ((1 << ct_log2) < ct) ++ct_log2;

    for (int t0 = 0; t0 < T_SZ; t0 += ct) {
        const int mtiles = (B_SZ * ct) / 128;
        pre_gemm<<<dim3(mtiles * 13), dim3(256), 0, stream>>>(
            x, Wih, bih, bhh, pre, t0, ct_log2);
        lstm_rec<<<dim3(B_SZ), dim3(448), 0, stream>>>(
            pre, Whh, Wout, bout, state, out, t0, ct);
    }
}

// Round 2
// 5740.802 us; speedup vs baseline: 10.0302x; 10.0302x over previous
//
#include <hip/hip_runtime.h>
#include <hip/hip_bf16.h>

#define B_SZ 512
#define T_SZ 512
#define D_SZ 256
#define H_SZ 200
#define G4   800   // 4*H

typedef __attribute__((ext_vector_type(8))) short short8;
typedef __attribute__((ext_vector_type(4))) short short4v;
typedef __attribute__((ext_vector_type(4))) float f32x4;

__device__ __forceinline__ unsigned short f2bf(float x) {
    unsigned u = __builtin_bit_cast(unsigned, x);
    unsigned r = (u + 0x7FFFu + ((u >> 16) & 1u)) >> 16;
    return (unsigned short)r;
}
__device__ __forceinline__ float sigm(float v) { return 1.f / (1.f + __expf(-v)); }

// ---------------------------------------------------------------------------
// Kernel 1: pre[tc][g][b] = sum_d x[b][t0+tc][d] * W_ih[g][d] + b_ih[g] + b_hh[g]
// M = 512*C_T with m = tc*512 + b; N = 800 (13 tiles of 64); K = 256. fp32 VALU.
// ---------------------------------------------------------------------------
__global__ __launch_bounds__(256)
void pre_gemm(const float* __restrict__ x, const float* __restrict__ Wih,
              const float* __restrict__ bih, const float* __restrict__ bhh,
              float* __restrict__ pre, int t0)
{
    const int nt = blockIdx.x % 13;
    const int mt = blockIdx.x / 13;
    const int n0 = nt * 64;
    const int tc = mt >> 2;              // 4 M-tiles of 128 per timestep
    const int b_base = (mt & 3) * 128;

    __shared__ float As[128 * 16];   // swizzled [r][(k + 4*((r>>3)&3)) & 15]
    __shared__ float Bs[16 * 68];    // [k][n], stride 68

    const int tid = threadIdx.x;
    const int tm = tid >> 4;
    const int tn = tid & 15;

    float acc[8][4];
    #pragma unroll
    for (int i = 0; i < 8; ++i)
        #pragma unroll
        for (int j = 0; j < 4; ++j) acc[i][j] = 0.f;

    const int r  = tid >> 1;
    const int kh = (tid & 1) * 8;
    const int b  = b_base + r;
    const float* xrow_base = x + ((size_t)b * T_SZ + t0 + tc) * D_SZ;
    const int rotA = 4 * ((r >> 3) & 3);

    const int nb = tid >> 2;
    const int kb = (tid & 3) * 4;
    const bool bvalid = (n0 + nb) < G4;
    const float* wrow_base = Wih + (size_t)(n0 + nb) * D_SZ;

    for (int k0 = 0; k0 < D_SZ; k0 += 16) {
        float4 av0 = *(const float4*)(xrow_base + k0 + kh);
        float4 av1 = *(const float4*)(xrow_base + k0 + kh + 4);
        float4 bv;
        if (bvalid) bv = *(const float4*)(wrow_base + k0 + kb);
        else        bv = make_float4(0.f, 0.f, 0.f, 0.f);

        __syncthreads();

        *(float4*)&As[r * 16 + ((kh     + rotA) & 15)] = av0;
        *(float4*)&As[r * 16 + ((kh + 4 + rotA) & 15)] = av1;
        Bs[(kb + 0) * 68 + nb] = bv.x;
        Bs[(kb + 1) * 68 + nb] = bv.y;
        Bs[(kb + 2) * 68 + nb] = bv.z;
        Bs[(kb + 3) * 68 + nb] = bv.w;

        __syncthreads();

        const int rotR = 4 * (tm & 3);
        #pragma unroll
        for (int kg = 0; kg < 4; ++kg) {
            float4 bf[4];
            #pragma unroll
            for (int j = 0; j < 4; ++j)
                bf[j] = *(const float4*)&Bs[(kg * 4 + j) * 68 + tn * 4];
            #pragma unroll
            for (int i = 0; i < 8; ++i) {
                const float4 af = *(const float4*)&As[(tm * 8 + i) * 16 + ((kg * 4 + rotR) & 15)];
                acc[i][0] += af.x * bf[0].x + af.y * bf[1].x + af.z * bf[2].x + af.w * bf[3].x;
                acc[i][1] += af.x * bf[0].y + af.y * bf[1].y + af.z * bf[2].y + af.w * bf[3].y;
                acc[i][2] += af.x * bf[0].z + af.y * bf[1].z + af.z * bf[2].z + af.w * bf[3].z;
                acc[i][3] += af.x * bf[0].w + af.y * bf[1].w + af.z * bf[2].w + af.w * bf[3].w;
            }
        }
    }

    // epilogue: pre[tc][g][b], contiguous in b per thread (2x float4 per g-col)
    const int bcol = b_base + tm * 8;
    #pragma unroll
    for (int j = 0; j < 4; ++j) {
        const int g = n0 + tn * 4 + j;
        if (g < G4) {
            const float bi = bih[g] + bhh[g];
            float* dst = pre + ((size_t)tc * G4 + g) * 512 + bcol;
            float4 v0 = make_float4(acc[0][j] + bi, acc[1][j] + bi, acc[2][j] + bi, acc[3][j] + bi);
            float4 v1 = make_float4(acc[4][j] + bi, acc[5][j] + bi, acc[6][j] + bi, acc[7][j] + bi);
            *(float4*)dst       = v0;
            *(float4*)(dst + 4) = v1;
        }
    }
}

// ---------------------------------------------------------------------------
// Kernel 2: LSTM recurrence. 32 WGs x 512 threads; one WG per 16 batches.
// W_hh bf16 resident in MFMA A-fragments across 8 waves (<=7 gate-tiles/wave).
// Per step: acc <- pre (global, coalesced); acc += Whh*h via 16x16x32 bf16 MFMA;
// activation in epilogue -> gates LDS (stride 17); elementwise c/h update;
// h -> bf16 hT LDS (stride 232) for next step's B-fragments.
// ---------------------------------------------------------------------------
#define HT_STRIDE 232
#define GST 17

__global__ __launch_bounds__(512)
void lstm_rec(const float* __restrict__ pre,   // [C_T][800][512]
              const float* __restrict__ Whh,   // [800][200]
              const float* __restrict__ Wout,  // [102400]
              const float* __restrict__ bout,  // [1]
              float* __restrict__ state,       // h[512][200], c[512][200], oa[512][200]
              float* __restrict__ out,         // [512]
              int t0, int C_T)
{
    const int b0   = blockIdx.x * 16;
    const int tid  = threadIdx.x;
    const int lane = tid & 63;
    const int wv   = tid >> 6;
    const int col  = lane & 15;
    const int q    = lane >> 4;

    __shared__ float gates[G4 * GST];                    // 54.4 KB
    __shared__ __align__(16) short hT[16 * HT_STRIDE];   // 7.4 KB

    // wave -> gate-tile assignment (50 tiles of 16 gates)
    const int ntile = (wv < 2) ? 7 : 6;
    const int tbase = (wv < 2) ? wv * 7 : 14 + (wv - 2) * 6;

    // ---- load W_hh fragments (bf16) ----
    short8  aw[7][6];
#if __has_builtin(__builtin_amdgcn_mfma_f32_16x16x16bf16_1k)
    short4v aw6[7];
#else
    short8  aw6[7];
#endif
    #pragma unroll
    for (int j = 0; j < 7; ++j) {
        if (j < ntile) {
            const int g = (tbase + j) * 16 + col;
            const float* wr = Whh + (size_t)g * H_SZ;
            #pragma unroll
            for (int kc = 0; kc < 6; ++kc) {
                const int k = kc * 32 + q * 8;
                float4 f0 = *(const float4*)(wr + k);
                float4 f1 = *(const float4*)(wr + k + 4);
                short8 s;
                s[0] = (short)f2bf(f0.x); s[1] = (short)f2bf(f0.y);
                s[2] = (short)f2bf(f0.z); s[3] = (short)f2bf(f0.w);
                s[4] = (short)f2bf(f1.x); s[5] = (short)f2bf(f1.y);
                s[6] = (short)f2bf(f1.z); s[7] = (short)f2bf(f1.w);
                aw[j][kc] = s;
            }
#if __has_builtin(__builtin_amdgcn_mfma_f32_16x16x16bf16_1k)
            // tail k = 192 + q*4 + jj (jj<4), valid for q<2
            short4v t4 = (short4v)0;
            if (q < 2) {
                float4 f = *(const float4*)(wr + 192 + q * 4);
                t4[0] = (short)f2bf(f.x); t4[1] = (short)f2bf(f.y);
                t4[2] = (short)f2bf(f.z); t4[3] = (short)f2bf(f.w);
            }
            aw6[j] = t4;
#else
            // tail k = 192 + q*8 + jj (jj<8), valid for q==0
            short8 t8 = (short8)0;
            if (q == 0) {
                float4 f0 = *(const float4*)(wr + 192);
                float4 f1 = *(const float4*)(wr + 196);
                t8[0] = (short)f2bf(f0.x); t8[1] = (short)f2bf(f0.y);
                t8[2] = (short)f2bf(f0.z); t8[3] = (short)f2bf(f0.w);
                t8[4] = (short)f2bf(f1.x); t8[5] = (short)f2bf(f1.y);
                t8[6] = (short)f2bf(f1.z); t8[7] = (short)f2bf(f1.w);
            }
            aw6[j] = t8;
#endif
        }
    }

    float* h_st  = state;
    float* c_st  = state + (size_t)B_SZ * H_SZ;
    float* oa_st = state + (size_t)2 * B_SZ * H_SZ;

    // ---- init hT (bf16 h, zero-padded k>=200) ----
    {
        const int n = tid >> 5, hs = tid & 31;
        #pragma unroll
        for (int jj = 0; jj < 8; ++jj) {
            const int k = hs + 32 * jj;
            if (k < HT_STRIDE) {
                short v = 0;
                if (t0 > 0 && k < H_SZ) v = (short)f2bf(h_st[(size_t)(b0 + n) * H_SZ + k]);
                hT[n * HT_STRIDE + k] = v;
            }
        }
    }

    // ---- per-thread c / output-accumulator state ----
    const int n_ew = tid >> 5;   // batch col 0..15
    const int hs   = tid & 31;
    float c[7], oa[7];
    #pragma unroll
    for (int j = 0; j < 7; ++j) { c[j] = 0.f; oa[j] = 0.f; }
    if (t0 > 0) {
        #pragma unroll
        for (int j = 0; j < 7; ++j) {
            const int h = hs + 32 * j;
            if (h < H_SZ) {
                c[j]  = c_st [(size_t)(b0 + n_ew) * H_SZ + h];
                oa[j] = oa_st[(size_t)(b0 + n_ew) * H_SZ + h];
            }
        }
    }
    __syncthreads();

    const short* hrow = hT + col * HT_STRIDE;

    for (int tc = 0; tc < C_T; ++tc) {
        // ===== MFMA phase: acc = pre + Whh*h, activation, write gates =====
        f32x4 acc[7];
        const float* pcol = pre + (size_t)tc * G4 * 512 + b0 + col;
        #pragma unroll
        for (int j = 0; j < 7; ++j) {
            if (j < ntile) {
                const int g0 = (tbase + j) * 16 + q * 4;
                const float* pp = pcol + (size_t)g0 * 512;
                f32x4 a;
                a[0] = pp[0]; a[1] = pp[512]; a[2] = pp[1024]; a[3] = pp[1536];
                acc[j] = a;
            }
        }
        #pragma unroll
        for (int kc = 0; kc < 6; ++kc) {
            short8 bf = *(const short8*)(hrow + kc * 32 + q * 8);
            #pragma unroll
            for (int j = 0; j < 7; ++j)
                if (j < ntile)
                    acc[j] = __builtin_amdgcn_mfma_f32_16x16x32_bf16(aw[j][kc], bf, acc[j], 0, 0, 0);
        }
#if __has_builtin(__builtin_amdgcn_mfma_f32_16x16x16bf16_1k)
        {
            short4v bt = *(const short4v*)(hrow + 192 + q * 4);
            #pragma unroll
            for (int j = 0; j < 7; ++j)
                if (j < ntile)
                    acc[j] = __builtin_amdgcn_mfma_f32_16x16x16bf16_1k(aw6[j], bt, acc[j], 0, 0, 0);
        }
#else
        {
            short8 bt = *(const short8*)(hrow + 192 + q * 8);
            #pragma unroll
            for (int j = 0; j < 7; ++j)
                if (j < ntile)
                    acc[j] = __builtin_amdgcn_mfma_f32_16x16x32_bf16(aw6[j], bt, acc[j], 0, 0, 0);
        }
#endif
        // activation in epilogue: i,f,o sigmoid; g (400..599) tanh
        #pragma unroll
        for (int j = 0; j < 7; ++j) {
            if (j < ntile) {
                const int gb = (tbase + j) * 16 + q * 4;
                #pragma unroll
                for (int i = 0; i < 4; ++i) {
                    const int ga = gb + i;
                    const float v = acc[j][i];
                    const bool isg = (ga >= 400) && (ga < 600);
                    const float e = __expf(isg ? -2.f * v : -v);
                    const float s = 1.f / (1.f + e);
                    gates[ga * GST + col] = isg ? (2.f * s - 1.f) : s;
                }
            }
        }
        __syncthreads();

        // ===== elementwise phase: c/h update, oa accumulate, write hT =====
        const int t = t0 + tc;
        #pragma unroll
        for (int j = 0; j < 7; ++j) {
            const int h = hs + 32 * j;
            if (h < H_SZ) {
                const int base = h * GST + n_ew;
                const float ig = gates[base];
                const float fg = gates[base + 200 * GST];
                const float gg = gates[base + 400 * GST];
                const float og = gates[base + 600 * GST];
                const float cn = fg * c[j] + ig * gg;
                c[j] = cn;
                const float th = 2.f * sigm(2.f * cn) - 1.f;
                const float hv = og * th;
                oa[j] += hv * Wout[(size_t)t * H_SZ + h];
                hT[n_ew * HT_STRIDE + h] = (short)f2bf(hv);
                if (tc == C_T - 1) h_st[(size_t)(b0 + n_ew) * H_SZ + h] = hv;
            }
        }
        __syncthreads();
    }

    if (t0 + C_T >= T_SZ) {
        // final output: out[b] = sum_h oa + bias
        float s = 0.f;
        #pragma unroll
        for (int j = 0; j < 7; ++j) s += oa[j];
        gates[tid] = s;
        __syncthreads();
        if (tid < 16) {
            float r = 0.f;
            #pragma unroll
            for (int k = 0; k < 32; ++k) r += gates[tid * 32 + k];
            out[b0 + tid] = r + bout[0];
        }
    } else {
        #pragma unroll
        for (int j = 0; j < 7; ++j) {
            const int h = hs + 32 * j;
            if (h < H_SZ) {
                c_st [(size_t)(b0 + n_ew) * H_SZ + h] = c[j];
                oa_st[(size_t)(b0 + n_ew) * H_SZ + h] = oa[j];
            }
        }
    }
}

// ---------------------------------------------------------------------------
extern "C" void kernel_launch(void* const* d_in, const int* in_sizes, int n_in,
                              void* d_out, int out_size, void* d_ws, size_t ws_size,
                              hipStream_t stream)
{
    const float* x    = (const float*)d_in[0];
    const float* Wih  = (const float*)d_in[1];
    const float* Whh  = (const float*)d_in[2];
    const float* bih  = (const float*)d_in[3];
    const float* bhh  = (const float*)d_in[4];
    const float* Wout = (const float*)d_in[5];
    const float* bout = (const float*)d_in[6];
    float* out = (float*)d_out;

    // ws layout: [state: 3 * 512 * 200 fp32][pre: C_T * 800 * 512 fp32]
    const size_t state_bytes = (size_t)3 * B_SZ * H_SZ * sizeof(float);
    float* state = (float*)d_ws;
    float* pre   = (float*)((char*)d_ws + state_bytes);

    int ct = 512;
    while (ct > 8 &&
           state_bytes + (size_t)ct * G4 * 512 * sizeof(float) > ws_size)
        ct >>= 1;

    for (int t0 = 0; t0 < T_SZ; t0 += ct) {
        pre_gemm<<<dim3(4 * ct * 13), dim3(256), 0, stream>>>(
            x, Wih, bih, bhh, pre, t0);
        lstm_rec<<<dim3(32), dim3(512), 0, stream>>>(
            pre, Whh, Wout, bout, state, out, t0, ct);
    }
}

// Round 3
// 3193.271 us; speedup vs baseline: 18.0321x; 1.7978x over previous
//
#include <hip/hip_runtime.h>
#include <hip/hip_bf16.h>

#define B_SZ 512
#define T_SZ 512
#define D_SZ 256
#define H_SZ 200
#define G4   800   // 4*H
#define NSUB 50    // gate subtiles of 16
#define HT_STRIDE 232
#define GSTRIDE 804

typedef __attribute__((ext_vector_type(8))) short short8;
typedef __attribute__((ext_vector_type(4))) short short4v;
typedef __attribute__((ext_vector_type(4))) float f32x4;

__device__ __forceinline__ unsigned short f2bf(float x) {
    unsigned u = __builtin_bit_cast(unsigned, x);
    unsigned r = (u + 0x7FFFu + ((u >> 16) & 1u)) >> 16;
    return (unsigned short)r;
}
__device__ __forceinline__ float sigm(float v) { return 1.f / (1.f + __expf(-v)); }

__device__ __forceinline__ void gl_lds16(const void* g, void* l) {
    __builtin_amdgcn_global_load_lds(
        (const __attribute__((address_space(1))) unsigned int*)g,
        (__attribute__((address_space(3))) unsigned int*)l, 16, 0, 0);
}

// ---------------------------------------------------------------------------
// Kernel 0: fp32 -> bf16 conversion (x and W_ih), float4 -> 4xbf16 packed
// ---------------------------------------------------------------------------
__global__ __launch_bounds__(256)
void cvt_bf16(const float* __restrict__ src, unsigned short* __restrict__ dst, int n4)
{
    int i = blockIdx.x * 256 + threadIdx.x;
    const int stride = gridDim.x * 256;
    for (; i < n4; i += stride) {
        float4 v = ((const float4*)src)[i];
        unsigned a = (unsigned)f2bf(v.x) | ((unsigned)f2bf(v.y) << 16);
        unsigned b = (unsigned)f2bf(v.z) | ((unsigned)f2bf(v.w) << 16);
        ((uint2*)dst)[i] = make_uint2(a, b);
    }
}

// ---------------------------------------------------------------------------
// Kernel 1: pre = x@W_ih^T + b_ih + b_hh, bf16 MFMA, output bf16 in layout
// pre[tt][S(50)][q(4)][b(512)][i(4)]  (g = S*16 + q*4 + i)
// Block 256 thr (4 waves), tile: 256 gates (wave w -> g w*64..w*64+63) x 64 b.
// Grid: (ct, 8 btiles, 4 gtiles). K=256 in 8 chunks of 32, global_load_lds.
// ---------------------------------------------------------------------------
__global__ __launch_bounds__(256)
void pre_gemm(const unsigned short* __restrict__ xbf,   // [512][512][256] bf16
              const unsigned short* __restrict__ wbf,   // [800][256] bf16
              const float* __restrict__ bih, const float* __restrict__ bhh,
              unsigned short* __restrict__ pre, int t0)
{
    const int tt = blockIdx.x;
    const int t  = t0 + tt;
    const int b0 = blockIdx.y * 64;
    const int g0 = blockIdx.z * 256;

    __shared__ unsigned short Al[256 * 32];  // 16 KB  [local g][k] k-contig
    __shared__ unsigned short Bl[64 * 32];   //  4 KB  [local b][k]

    const int tid  = threadIdx.x;
    const int w    = tid >> 6;
    const int lane = tid & 63;
    const int col  = lane & 15, q = lane >> 4;

    f32x4 acc[4][4];
    #pragma unroll
    for (int i = 0; i < 4; ++i)
        #pragma unroll
        for (int j = 0; j < 4; ++j) acc[i][j] = (f32x4)0.f;

    const int arow = w * 64 + (lane >> 2);     // + j*16
    const int akoff = (lane & 3) * 8;
    const int brow = b0 + w * 16 + (lane >> 2);

    for (int kc = 0; kc < 8; ++kc) {
        const int d0 = kc * 32;
        if (kc) __syncthreads();
        #pragma unroll
        for (int j = 0; j < 4; ++j) {
            int g = g0 + arow + j * 16;
            if (g > G4 - 1) g = G4 - 1;            // clamp (stores skipped later)
            gl_lds16(wbf + (size_t)g * D_SZ + d0 + akoff,
                     (void*)(Al + (w * 64 + j * 16) * 32));
        }
        gl_lds16(xbf + ((size_t)brow * T_SZ + t) * D_SZ + d0 + akoff,
                 (void*)(Bl + (w * 16) * 32));
        __syncthreads();

        short8 af[4], bv[4];
        #pragma unroll
        for (int s = 0; s < 4; ++s)
            af[s] = *(const short8*)&Al[(w * 64 + s * 16 + col) * 32 + q * 8];
        #pragma unroll
        for (int s = 0; s < 4; ++s)
            bv[s] = *(const short8*)&Bl[(s * 16 + col) * 32 + q * 8];
        #pragma unroll
        for (int gs = 0; gs < 4; ++gs)
            #pragma unroll
            for (int bs = 0; bs < 4; ++bs)
                acc[gs][bs] = __builtin_amdgcn_mfma_f32_16x16x32_bf16(af[gs], bv[bs], acc[gs][bs], 0, 0, 0);
    }

    // epilogue: lane holds D[m=q*4+reg (g), n=col (b)]; 4 g contiguous -> 8B store
    #pragma unroll
    for (int gs = 0; gs < 4; ++gs) {
        const int S = blockIdx.z * 16 + w * 4 + gs;
        if (S < NSUB) {
            const int gq = S * 16 + q * 4;
            const float4 bi = *(const float4*)&bih[gq];
            const float4 bh = *(const float4*)&bhh[gq];
            #pragma unroll
            for (int bs = 0; bs < 4; ++bs) {
                f32x4 a = acc[gs][bs];
                unsigned lo = (unsigned)f2bf(a[0] + bi.x + bh.x) |
                              ((unsigned)f2bf(a[1] + bi.y + bh.y) << 16);
                unsigned hi = (unsigned)f2bf(a[2] + bi.z + bh.z) |
                              ((unsigned)f2bf(a[3] + bi.w + bh.w) << 16);
                const size_t idx = (((size_t)tt * NSUB + S) * 4 + q) * 512 + (b0 + bs * 16 + col);
                ((uint2*)pre)[idx] = make_uint2(lo, hi);
            }
        }
    }
}

// ---------------------------------------------------------------------------
// Kernel 2: LSTM recurrence. 256 WGs x 512 thr; 2 batches per WG.
// W_hh bf16 resident as MFMA A-fragments (8 waves x <=7 gate-subtiles).
// Per step: acc <- prefetched pre (bf16); MFMA Whh*h; raw acc -> gates LDS;
// barrier; activations + c/h update + Wout accumulate; h -> bf16 hT; barrier.
// ---------------------------------------------------------------------------
__global__ __launch_bounds__(512, 2)
void lstm_rec(const unsigned short* __restrict__ pre,  // [ct][50][4][512][4] bf16
              const float* __restrict__ Whh,   // [800][200]
              const float* __restrict__ Wout,  // [512*200]
              const float* __restrict__ bout,
              float* __restrict__ state,       // h,c,oa each [512][200]
              float* __restrict__ out,         // [512]
              int t0, int C_T)
{
    const int bk = blockIdx.x;
    const int cidx = (bk >> 3) + (bk & 7) * 32;   // XCD-swizzle: line-sharing WGs on same XCD
    const int b0 = cidx * 2;

    const int tid = threadIdx.x, lane = tid & 63, wv = tid >> 6;
    const int col = lane & 15, q = lane >> 4;

    __shared__ float gates[2 * GSTRIDE];                 // raw gate pre-activations
    __shared__ __align__(16) short hT[16 * HT_STRIDE];   // bf16 h, rows 2..15 zero
    __shared__ float redbuf[8];

    // wave -> gate-subtile assignment (50 subtiles of 16 gates)
    const int ntile = (wv < 2) ? 7 : 6;
    const int tbase = (wv < 2) ? wv * 7 : 14 + (wv - 2) * 6;

    // ---- W_hh fragments (bf16) ----
    short8  aw[7][6];
#if __has_builtin(__builtin_amdgcn_mfma_f32_16x16x16bf16_1k)
    short4v aw6[7];
#else
    short8  aw6[7];
#endif
    #pragma unroll
    for (int j = 0; j < 7; ++j) {
        if (j < ntile) {
            const int g = (tbase + j) * 16 + col;
            const float* wr = Whh + (size_t)g * H_SZ;
            #pragma unroll
            for (int kc = 0; kc < 6; ++kc) {
                const int k = kc * 32 + q * 8;
                float4 f0 = *(const float4*)(wr + k);
                float4 f1 = *(const float4*)(wr + k + 4);
                short8 s;
                s[0] = (short)f2bf(f0.x); s[1] = (short)f2bf(f0.y);
                s[2] = (short)f2bf(f0.z); s[3] = (short)f2bf(f0.w);
                s[4] = (short)f2bf(f1.x); s[5] = (short)f2bf(f1.y);
                s[6] = (short)f2bf(f1.z); s[7] = (short)f2bf(f1.w);
                aw[j][kc] = s;
            }
#if __has_builtin(__builtin_amdgcn_mfma_f32_16x16x16bf16_1k)
            short4v t4 = (short4v)0;
            if (q < 2) {
                float4 f = *(const float4*)(wr + 192 + q * 4);
                t4[0] = (short)f2bf(f.x); t4[1] = (short)f2bf(f.y);
                t4[2] = (short)f2bf(f.z); t4[3] = (short)f2bf(f.w);
            }
            aw6[j] = t4;
#else
            short8 t8 = (short8)0;
            if (q == 0) {
                float4 f0 = *(const float4*)(wr + 192);
                float4 f1 = *(const float4*)(wr + 196);
                t8[0] = (short)f2bf(f0.x); t8[1] = (short)f2bf(f0.y);
                t8[2] = (short)f2bf(f0.z); t8[3] = (short)f2bf(f0.w);
                t8[4] = (short)f2bf(f1.x); t8[5] = (short)f2bf(f1.y);
                t8[6] = (short)f2bf(f1.z); t8[7] = (short)f2bf(f1.w);
            }
            aw6[j] = t8;
#endif
        }
    }

    float* h_st  = state;
    float* c_st  = state + (size_t)B_SZ * H_SZ;
    float* oa_st = state + (size_t)2 * B_SZ * H_SZ;

    // ---- init hT ----
    for (int i = tid; i < 16 * HT_STRIDE; i += 512) {
        int r = i / HT_STRIDE, k = i - r * HT_STRIDE;
        short v = 0;
        if (t0 > 0 && r < 2 && k < H_SZ) v = (short)f2bf(h_st[(size_t)(b0 + r) * H_SZ + k]);
        hT[i] = v;
    }

    // ---- elementwise thread state ----
    const int n_ew = tid >> 8;        // batch 0..1
    const int h_ew = tid & 255;
    const bool ewv = (h_ew < H_SZ);
    float c_v = 0.f, oa_v = 0.f, wout_c = 0.f;
    if (ewv) {
        wout_c = Wout[(size_t)t0 * H_SZ + h_ew];
        if (t0 > 0) {
            c_v  = c_st [(size_t)(b0 + n_ew) * H_SZ + h_ew];
            oa_v = oa_st[(size_t)(b0 + n_ew) * H_SZ + h_ew];
        }
    }

    // ---- initial pre prefetch (tc = 0) ----
    const uint2* preu = (const uint2*)pre;
    size_t pbase[7];
    uint2 pf[7];
    #pragma unroll
    for (int j = 0; j < 7; ++j) {
        pbase[j] = ((size_t)(tbase + j) * 4 + q) * 512 + b0 + col;
        pf[j] = make_uint2(0u, 0u);
        if (col < 2 && j < ntile) pf[j] = preu[pbase[j]];
    }

    __syncthreads();

    const short* hrow = hT + col * HT_STRIDE;

    for (int tc = 0; tc < C_T; ++tc) {
        // acc <- prefetched pre
        f32x4 acc[7];
        #pragma unroll
        for (int j = 0; j < 7; ++j) {
            uint2 p = pf[j];
            f32x4 a;
            a[0] = __builtin_bit_cast(float, p.x << 16);
            a[1] = __builtin_bit_cast(float, p.x & 0xFFFF0000u);
            a[2] = __builtin_bit_cast(float, p.y << 16);
            a[3] = __builtin_bit_cast(float, p.y & 0xFFFF0000u);
            acc[j] = a;
        }
        // prefetch next step's pre
        {
            const int tcn = (tc + 1 < C_T) ? tc + 1 : tc;
            const size_t toff = (size_t)tcn * (NSUB * 4 * 512);
            #pragma unroll
            for (int j = 0; j < 7; ++j)
                if (col < 2 && j < ntile) pf[j] = preu[toff + pbase[j]];
        }
        // MFMA: acc += Whh * h
        #pragma unroll
        for (int kc = 0; kc < 6; ++kc) {
            short8 bf = *(const short8*)(hrow + kc * 32 + q * 8);
            #pragma unroll
            for (int j = 0; j < 7; ++j)
                if (j < ntile)
                    acc[j] = __builtin_amdgcn_mfma_f32_16x16x32_bf16(aw[j][kc], bf, acc[j], 0, 0, 0);
        }
#if __has_builtin(__builtin_amdgcn_mfma_f32_16x16x16bf16_1k)
        {
            short4v bt = *(const short4v*)(hrow + 192 + q * 4);
            #pragma unroll
            for (int j = 0; j < 7; ++j)
                if (j < ntile)
                    acc[j] = __builtin_amdgcn_mfma_f32_16x16x16bf16_1k(aw6[j], bt, acc[j], 0, 0, 0);
        }
#else
        {
            short8 bt = *(const short8*)(hrow + 192 + q * 8);
            #pragma unroll
            for (int j = 0; j < 7; ++j)
                if (j < ntile)
                    acc[j] = __builtin_amdgcn_mfma_f32_16x16x32_bf16(aw6[j], bt, acc[j], 0, 0, 0);
        }
#endif
        // raw gates -> LDS (only valid batch cols)
        if (col < 2) {
            #pragma unroll
            for (int j = 0; j < 7; ++j)
                if (j < ntile)
                    *(f32x4*)&gates[col * GSTRIDE + (tbase + j) * 16 + q * 4] = acc[j];
        }
        __syncthreads();

        // elementwise: activations, c/h update, output accumulate
        if (ewv) {
            const int gb = n_ew * GSTRIDE + h_ew;
            const float gi = sigm(gates[gb]);
            const float gf = sigm(gates[gb + 200]);
            const float gg = 2.f * sigm(2.f * gates[gb + 400]) - 1.f;
            const float go = sigm(gates[gb + 600]);
            const float cn = gf * c_v + gi * gg;
            c_v = cn;
            const float hv = go * (2.f * sigm(2.f * cn) - 1.f);
            oa_v += hv * wout_c;
            hT[n_ew * HT_STRIDE + h_ew] = (short)f2bf(hv);
            if (t0 + C_T < T_SZ && tc == C_T - 1)
                h_st[(size_t)(b0 + n_ew) * H_SZ + h_ew] = hv;
            // prefetch next Wout column
            const int tn = (t0 + tc + 1 < T_SZ) ? t0 + tc + 1 : T_SZ - 1;
            wout_c = Wout[(size_t)tn * H_SZ + h_ew];
        }
        __syncthreads();
    }

    if (t0 + C_T >= T_SZ) {
        float v = oa_v;   // zero for invalid threads
        #pragma unroll
        for (int off = 32; off; off >>= 1) v += __shfl_down(v, off);
        if (lane == 0) redbuf[wv] = v;
        __syncthreads();
        if (tid < 2)
            out[b0 + tid] = redbuf[tid * 4] + redbuf[tid * 4 + 1] +
                            redbuf[tid * 4 + 2] + redbuf[tid * 4 + 3] + bout[0];
    } else if (ewv) {
        c_st [(size_t)(b0 + n_ew) * H_SZ + h_ew] = c_v;
        oa_st[(size_t)(b0 + n_ew) * H_SZ + h_ew] = oa_v;
    }
}

// ---------------------------------------------------------------------------
extern "C" void kernel_launch(void* const* d_in, const int* in_sizes, int n_in,
                              void* d_out, int out_size, void* d_ws, size_t ws_size,
                              hipStream_t stream)
{
    const float* x    = (const float*)d_in[0];
    const float* Wih  = (const float*)d_in[1];
    const float* Whh  = (const float*)d_in[2];
    const float* bih  = (const float*)d_in[3];
    const float* bhh  = (const float*)d_in[4];
    const float* Wout = (const float*)d_in[5];
    const float* bout = (const float*)d_in[6];
    float* out = (float*)d_out;

    // ws layout: state | xbf | wbf | pre
    char* ws = (char*)d_ws;
    float* state = (float*)ws;
    size_t off = (size_t)3 * B_SZ * H_SZ * sizeof(float);            // 1,228,800
    unsigned short* xbf = (unsigned short*)(ws + off);
    off += (size_t)B_SZ * T_SZ * D_SZ * 2;                           // +134,217,728
    unsigned short* wbf = (unsigned short*)(ws + off);
    off += (size_t)G4 * D_SZ * 2;                                    // +409,600
    unsigned short* pre = (unsigned short*)(ws + off);

    const size_t per_t = (size_t)NSUB * 4 * 512 * 4 * 2;             // 819,200 B
    int ct = 512;
    while (ct > 8 && off + (size_t)ct * per_t > ws_size) ct >>= 1;

    cvt_bf16<<<dim3(2048), dim3(256), 0, stream>>>(x, xbf, B_SZ * T_SZ * D_SZ / 4);
    cvt_bf16<<<dim3(64),   dim3(256), 0, stream>>>(Wih, wbf, G4 * D_SZ / 4);

    for (int t0 = 0; t0 < T_SZ; t0 += ct) {
        pre_gemm<<<dim3(ct, 8, 4), dim3(256), 0, stream>>>(
            xbf, wbf, bih, bhh, pre, t0);
        lstm_rec<<<dim3(256), dim3(512), 0, stream>>>(
            pre, Whh, Wout, bout, state, out, t0, ct);
    }
}

// Round 4
// 1872.039 us; speedup vs baseline: 30.7586x; 1.7058x over previous
//
#include <hip/hip_runtime.h>
#include <hip/hip_bf16.h>

#define B_SZ 512
#define T_SZ 512
#define D_SZ 256
#define H_SZ 200
#define G4   800   // 4*H
#define NSUB 50    // gate subtiles of 16
#define GST8 808   // gates stride (floats) per batch
#define GDUMP (2*GST8)
#define HTS  232   // hT row stride (shorts)
#define BS   8     // steps per LDS staging block

typedef __attribute__((ext_vector_type(8))) short short8;
typedef __attribute__((ext_vector_type(4))) short short4v;
typedef __attribute__((ext_vector_type(4))) float f32x4;

__device__ __forceinline__ unsigned short f2bf(float x) {
    unsigned u = __builtin_bit_cast(unsigned, x);
    unsigned r = (u + 0x7FFFu + ((u >> 16) & 1u)) >> 16;
    return (unsigned short)r;
}
__device__ __forceinline__ float sigm(float v) { return 1.f / (1.f + __expf(-v)); }

__device__ __forceinline__ void gl_lds16(const void* g, void* l) {
    __builtin_amdgcn_global_load_lds(
        (const __attribute__((address_space(1))) unsigned int*)g,
        (__attribute__((address_space(3))) unsigned int*)l, 16, 0, 0);
}

// ---------------------------------------------------------------------------
// Kernel 0: fp32 -> bf16 conversion
// ---------------------------------------------------------------------------
__global__ __launch_bounds__(256)
void cvt_bf16(const float* __restrict__ src, unsigned short* __restrict__ dst, int n4)
{
    int i = blockIdx.x * 256 + threadIdx.x;
    const int stride = gridDim.x * 256;
    for (; i < n4; i += stride) {
        float4 v = ((const float4*)src)[i];
        unsigned a = (unsigned)f2bf(v.x) | ((unsigned)f2bf(v.y) << 16);
        unsigned b = (unsigned)f2bf(v.z) | ((unsigned)f2bf(v.w) << 16);
        ((uint2*)dst)[i] = make_uint2(a, b);
    }
}

// ---------------------------------------------------------------------------
// Kernel 1: pre = x@W_ih^T + b_ih + b_hh, bf16 MFMA
// output layout pre[tt][S(50)][q(4)][b(512)][i(4)] bf16  (g = S*16 + q*4 + i)
// ---------------------------------------------------------------------------
__global__ __launch_bounds__(256)
void pre_gemm(const unsigned short* __restrict__ xbf,
              const unsigned short* __restrict__ wbf,
              const float* __restrict__ bih, const float* __restrict__ bhh,
              unsigned short* __restrict__ pre, int t0)
{
    const int tt = blockIdx.x;
    const int t  = t0 + tt;
    const int b0 = blockIdx.y * 64;
    const int g0 = blockIdx.z * 256;

    __shared__ unsigned short Al[256 * 32];
    __shared__ unsigned short Bl[64 * 32];

    const int tid  = threadIdx.x;
    const int w    = tid >> 6;
    const int lane = tid & 63;
    const int col  = lane & 15, q = lane >> 4;

    f32x4 acc[4][4];
    #pragma unroll
    for (int i = 0; i < 4; ++i)
        #pragma unroll
        for (int j = 0; j < 4; ++j) acc[i][j] = (f32x4)0.f;

    const int arow = w * 64 + (lane >> 2);
    const int akoff = (lane & 3) * 8;
    const int brow = b0 + w * 16 + (lane >> 2);

    for (int kc = 0; kc < 8; ++kc) {
        const int d0 = kc * 32;
        if (kc) __syncthreads();
        #pragma unroll
        for (int j = 0; j < 4; ++j) {
            int g = g0 + arow + j * 16;
            if (g > G4 - 1) g = G4 - 1;
            gl_lds16(wbf + (size_t)g * D_SZ + d0 + akoff,
                     (void*)(Al + (w * 64 + j * 16) * 32));
        }
        gl_lds16(xbf + ((size_t)brow * T_SZ + t) * D_SZ + d0 + akoff,
                 (void*)(Bl + (w * 16) * 32));
        __syncthreads();

        short8 af[4], bv[4];
        #pragma unroll
        for (int s = 0; s < 4; ++s)
            af[s] = *(const short8*)&Al[(w * 64 + s * 16 + col) * 32 + q * 8];
        #pragma unroll
        for (int s = 0; s < 4; ++s)
            bv[s] = *(const short8*)&Bl[(s * 16 + col) * 32 + q * 8];
        #pragma unroll
        for (int gs = 0; gs < 4; ++gs)
            #pragma unroll
            for (int bs = 0; bs < 4; ++bs)
                acc[gs][bs] = __builtin_amdgcn_mfma_f32_16x16x32_bf16(af[gs], bv[bs], acc[gs][bs], 0, 0, 0);
    }

    #pragma unroll
    for (int gs = 0; gs < 4; ++gs) {
        const int S = blockIdx.z * 16 + w * 4 + gs;
        if (S < NSUB) {
            const int gq = S * 16 + q * 4;
            const float4 bi = *(const float4*)&bih[gq];
            const float4 bh = *(const float4*)&bhh[gq];
            #pragma unroll
            for (int bs = 0; bs < 4; ++bs) {
                f32x4 a = acc[gs][bs];
                unsigned lo = (unsigned)f2bf(a[0] + bi.x + bh.x) |
                              ((unsigned)f2bf(a[1] + bi.y + bh.y) << 16);
                unsigned hi = (unsigned)f2bf(a[2] + bi.z + bh.z) |
                              ((unsigned)f2bf(a[3] + bi.w + bh.w) << 16);
                const size_t idx = (((size_t)tt * NSUB + S) * 4 + q) * 512 + (b0 + bs * 16 + col);
                ((uint2*)pre)[idx] = make_uint2(lo, hi);
            }
        }
    }
}

// ---------------------------------------------------------------------------
// Kernel 2: LSTM recurrence. 256 WGs x 512 thr (8 waves); 2 batches per WG.
// Branchless hot loop: every wave runs exactly 7 tiles (dummy tiles clamp to
// tile 49 and dump their gate store to an LDS scrap zone via cndmask address).
// pre staged 8 steps at a time into double-buffered LDS via global_load_lds.
// ---------------------------------------------------------------------------
__global__ __launch_bounds__(512, 2)
void lstm_rec(const unsigned short* __restrict__ pre,  // [ct][50][4][512][4] bf16
              const float* __restrict__ Whh,
              const float* __restrict__ Wout,
              const float* __restrict__ bout,
              float* __restrict__ state,       // h,c,oa each [512][200]
              float* __restrict__ out,
              int t0, int C_T)
{
    const int bk = blockIdx.x;
    const int cidx = (bk >> 3) + (bk & 7) * 32;   // XCD swizzle: line-sharers co-XCD
    const int b0 = cidx * 2;

    const int tid = threadIdx.x, lane = tid & 63, wv = tid >> 6;
    const int col = lane & 15, q = lane >> 4;

    __shared__ __align__(16) unsigned short preS[2 * BS * 1600]; // 51.2 KB
    __shared__ __align__(16) float gates[2 * GST8 + 256];        // 7.5 KB
    __shared__ __align__(16) short hT[3 * HTS];                  // 1.4 KB
    __shared__ float redbuf[8];

    // tiles: waves 0,1 -> 7 real; waves 2..7 -> 6 real + 1 dummy
    const int tbase = (wv < 2) ? wv * 7 : 14 + (wv - 2) * 6;

    int gaddr[7], pofs[7], tjv[7];
    #pragma unroll
    for (int j = 0; j < 7; ++j) {
        const int tr = tbase + j;
        const int tj = tr > 49 ? 49 : tr;
        tjv[j] = tj;
        const bool valid = (tr <= 49) && (col < 2);
        gaddr[j] = valid ? (col * GST8 + tj * 16 + q * 4) : (GDUMP + lane * 4);
        pofs[j]  = (tj * 4 + q) * 8 + (col & 1) * 4;   // shorts, within step slab
    }

    // ---- W_hh fragments (bf16), K padded: 6 x32-chunks + one x16 tail ----
    short8 aw[7][6];
#if __has_builtin(__builtin_amdgcn_mfma_f32_16x16x16bf16_1k)
    short4v aw6[7];
#else
    short8 aw6[7];
#endif
    #pragma unroll
    for (int j = 0; j < 7; ++j) {
        const int g = tjv[j] * 16 + col;
        const float* wr = Whh + (size_t)g * H_SZ;
        #pragma unroll
        for (int kc = 0; kc < 6; ++kc) {
            const int k = kc * 32 + q * 8;
            float4 f0 = *(const float4*)(wr + k);
            float4 f1 = *(const float4*)(wr + k + 4);
            short8 s;
            s[0] = (short)f2bf(f0.x); s[1] = (short)f2bf(f0.y);
            s[2] = (short)f2bf(f0.z); s[3] = (short)f2bf(f0.w);
            s[4] = (short)f2bf(f1.x); s[5] = (short)f2bf(f1.y);
            s[6] = (short)f2bf(f1.z); s[7] = (short)f2bf(f1.w);
            aw[j][kc] = s;
        }
#if __has_builtin(__builtin_amdgcn_mfma_f32_16x16x16bf16_1k)
        short4v t4 = (short4v)0;
        if (q < 2) {
            float4 f = *(const float4*)(wr + 192 + q * 4);
            t4[0] = (short)f2bf(f.x); t4[1] = (short)f2bf(f.y);
            t4[2] = (short)f2bf(f.z); t4[3] = (short)f2bf(f.w);
        }
        aw6[j] = t4;
#else
        short8 t8 = (short8)0;
        if (q == 0) {
            float4 f0 = *(const float4*)(wr + 192);
            float4 f1 = *(const float4*)(wr + 196);
            t8[0] = (short)f2bf(f0.x); t8[1] = (short)f2bf(f0.y);
            t8[2] = (short)f2bf(f0.z); t8[3] = (short)f2bf(f0.w);
            t8[4] = (short)f2bf(f1.x); t8[5] = (short)f2bf(f1.y);
            t8[6] = (short)f2bf(f1.z); t8[7] = (short)f2bf(f1.w);
        }
        aw6[j] = t8;
#endif
    }

    float* h_st  = state;
    float* c_st  = state + (size_t)B_SZ * H_SZ;
    float* oa_st = state + (size_t)2 * B_SZ * H_SZ;

    // ---- init hT (rows 0,1 = h for the 2 batches; row 2 = zeros; k>=200 zeros)
    for (int i = tid; i < 3 * HTS; i += 512) {
        const int r = i / HTS, k = i - r * HTS;
        short v = 0;
        if (t0 > 0 && r < 2 && k < H_SZ) v = (short)f2bf(h_st[(size_t)(b0 + r) * H_SZ + k]);
        hT[i] = v;
    }

    // ---- elementwise thread state ----
    const int n_ew = tid >> 8;
    const int h_ew = tid & 255;
    const bool ewv = (h_ew < H_SZ);
    float c_v = 0.f, oa_v = 0.f, wpf0 = 0.f, wpf1 = 0.f;
    if (ewv) {
        wpf0 = Wout[(size_t)t0 * H_SZ + h_ew];
        const int t1 = (t0 + 1 < T_SZ) ? t0 + 1 : T_SZ - 1;
        wpf1 = Wout[(size_t)t1 * H_SZ + h_ew];
        if (t0 > 0) {
            c_v  = c_st [(size_t)(b0 + n_ew) * H_SZ + h_ew];
            oa_v = oa_st[(size_t)(b0 + n_ew) * H_SZ + h_ew];
        }
    }

    const int nblk = C_T / BS;
    const char* preb = (const char*)pre;

    // ---- stage block 0 into buffer 0 (wave wv stages step wv) ----
    {
        const char* src = preb + ((size_t)wv * 200) * 4096 + (size_t)b0 * 8;
        unsigned short* dst = preS + (0 * BS + wv) * 1600;
        gl_lds16(src + (size_t)lane * 4096,         dst);
        gl_lds16(src + (size_t)(lane + 64) * 4096,  dst + 512);
        gl_lds16(src + (size_t)(lane + 128) * 4096, dst + 1024);
        gl_lds16(src + (size_t)(lane + 136) * 4096, dst + 1088);
    }
    __syncthreads();

    const short* hrow = hT + (col < 2 ? col : 2) * HTS;

    for (int blk = 0; blk < nblk; ++blk) {
        const int bn = blk & 1;
        // stage next block (clamped) into other buffer — drained by next barrier
        {
            const int nb = (blk + 1 < nblk) ? blk + 1 : blk;
            const char* src = preb + ((size_t)(nb * BS + wv) * 200) * 4096 + (size_t)b0 * 8;
            unsigned short* dst = preS + ((bn ^ 1) * BS + wv) * 1600;
            gl_lds16(src + (size_t)lane * 4096,         dst);
            gl_lds16(src + (size_t)(lane + 64) * 4096,  dst + 512);
            gl_lds16(src + (size_t)(lane + 128) * 4096, dst + 1024);
            gl_lds16(src + (size_t)(lane + 136) * 4096, dst + 1088);
        }
        const unsigned short* psb = preS + bn * (BS * 1600);

        for (int s = 0; s < BS; ++s) {
            const int tc = blk * BS + s;
            const unsigned short* ps = psb + s * 1600;

            // acc init from staged pre (bf16 -> f32)
            f32x4 acc[7];
            #pragma unroll
            for (int j = 0; j < 7; ++j) {
                const uint2 p = *(const uint2*)(ps + pofs[j]);
                f32x4 a;
                a[0] = __builtin_bit_cast(float, p.x << 16);
                a[1] = __builtin_bit_cast(float, p.x & 0xFFFF0000u);
                a[2] = __builtin_bit_cast(float, p.y << 16);
                a[3] = __builtin_bit_cast(float, p.y & 0xFFFF0000u);
                acc[j] = a;
            }
            // MFMA: acc += Whh * h   (branchless, uniform 7 tiles)
            #pragma unroll
            for (int kc = 0; kc < 6; ++kc) {
                const short8 bf = *(const short8*)(hrow + kc * 32 + q * 8);
                #pragma unroll
                for (int j = 0; j < 7; ++j)
                    acc[j] = __builtin_amdgcn_mfma_f32_16x16x32_bf16(aw[j][kc], bf, acc[j], 0, 0, 0);
            }
#if __has_builtin(__builtin_amdgcn_mfma_f32_16x16x16bf16_1k)
            {
                const short4v bt = *(const short4v*)(hrow + 192 + q * 4);
                #pragma unroll
                for (int j = 0; j < 7; ++j)
                    acc[j] = __builtin_amdgcn_mfma_f32_16x16x16bf16_1k(aw6[j], bt, acc[j], 0, 0, 0);
            }
#else
            {
                const short8 bt = *(const short8*)(hrow + 192 + q * 8);
                #pragma unroll
                for (int j = 0; j < 7; ++j)
                    acc[j] = __builtin_amdgcn_mfma_f32_16x16x32_bf16(aw6[j], bt, acc[j], 0, 0, 0);
            }
#endif
            // raw gates -> LDS (dummy/invalid lanes go to dump zone; no branch)
            #pragma unroll
            for (int j = 0; j < 7; ++j)
                *(f32x4*)&gates[gaddr[j]] = acc[j];
            __syncthreads();

            // elementwise: activations, c/h update, output accumulate
            if (ewv) {
                const int gb = n_ew * GST8 + h_ew;
                const float gi = sigm(gates[gb]);
                const float gf = sigm(gates[gb + 200]);
                const float gg = 2.f * sigm(2.f * gates[gb + 400]) - 1.f;
                const float go = sigm(gates[gb + 600]);
                const float cn = gf * c_v + gi * gg;
                c_v = cn;
                const float hv = go * (2.f * sigm(2.f * cn) - 1.f);
                oa_v += hv * wpf0;
                wpf0 = wpf1;
                const int tn = (t0 + tc + 2 < T_SZ) ? t0 + tc + 2 : T_SZ - 1;
                wpf1 = Wout[(size_t)tn * H_SZ + h_ew];
                hT[n_ew * HTS + h_ew] = (short)f2bf(hv);
                if (t0 + C_T < T_SZ && tc == C_T - 1)
                    h_st[(size_t)(b0 + n_ew) * H_SZ + h_ew] = hv;
            }
            __syncthreads();
        }
    }

    if (t0 + C_T >= T_SZ) {
        float v = oa_v;   // zero on inactive threads
        #pragma unroll
        for (int off = 32; off; off >>= 1) v += __shfl_down(v, off);
        if (lane == 0) redbuf[wv] = v;
        __syncthreads();
        if (tid < 2)
            out[b0 + tid] = redbuf[tid * 4] + redbuf[tid * 4 + 1] +
                            redbuf[tid * 4 + 2] + redbuf[tid * 4 + 3] + bout[0];
    } else if (ewv) {
        c_st [(size_t)(b0 + n_ew) * H_SZ + h_ew] = c_v;
        oa_st[(size_t)(b0 + n_ew) * H_SZ + h_ew] = oa_v;
    }
}

// ---------------------------------------------------------------------------
extern "C" void kernel_launch(void* const* d_in, const int* in_sizes, int n_in,
                              void* d_out, int out_size, void* d_ws, size_t ws_size,
                              hipStream_t stream)
{
    const float* x    = (const float*)d_in[0];
    const float* Wih  = (const float*)d_in[1];
    const float* Whh  = (const float*)d_in[2];
    const float* bih  = (const float*)d_in[3];
    const float* bhh  = (const float*)d_in[4];
    const float* Wout = (const float*)d_in[5];
    const float* bout = (const float*)d_in[6];
    float* out = (float*)d_out;

    // ws layout: state | xbf | wbf | pre
    char* ws = (char*)d_ws;
    float* state = (float*)ws;
    size_t off = (size_t)3 * B_SZ * H_SZ * sizeof(float);
    unsigned short* xbf = (unsigned short*)(ws + off);
    off += (size_t)B_SZ * T_SZ * D_SZ * 2;
    unsigned short* wbf = (unsigned short*)(ws + off);
    off += (size_t)G4 * D_SZ * 2;
    unsigned short* pre = (unsigned short*)(ws + off);

    const size_t per_t = (size_t)NSUB * 4 * 512 * 4 * 2;   // 819,200 B per step
    int ct = 512;
    while (ct > BS && off + (size_t)ct * per_t > ws_size) ct >>= 1;

    cvt_bf16<<<dim3(2048), dim3(256), 0, stream>>>(x, xbf, B_SZ * T_SZ * D_SZ / 4);
    cvt_bf16<<<dim3(64),   dim3(256), 0, stream>>>(Wih, wbf, G4 * D_SZ / 4);

    for (int t0 = 0; t0 < T_SZ; t0 += ct) {
        pre_gemm<<<dim3(ct, 8, 4), dim3(256), 0, stream>>>(
            xbf, wbf, bih, bhh, pre, t0);
        lstm_rec<<<dim3(256), dim3(512), 0, stream>>>(
            pre, Whh, Wout, bout, state, out, t0, ct);
    }
}